// Round 13
// baseline (119.289 us; speedup 1.0000x reference)
//
#include <hip/hip_runtime.h>
#include <hip/hip_bf16.h>

typedef short short8 __attribute__((ext_vector_type(8)));
typedef short short4v __attribute__((ext_vector_type(4)));
typedef float f32x4 __attribute__((ext_vector_type(4)));
typedef unsigned int uint2v __attribute__((ext_vector_type(2)));

#define NPTS 4096
#define BATCH 8
#define PTOT 32768
#define FEATS 128
#define KK 20
#define OUTC 64
#define PTS_PER_WAVE 8
#define WAVES 4

__device__ __forceinline__ unsigned short f2bf(float f){
  union { __hip_bfloat16 h; unsigned short u; } v;
  v.h = __hip_bfloat16(f);
  return v.u;
}

__device__ __forceinline__ void gload_lds16(const void* src, void* dst){
  __builtin_amdgcn_global_load_lds((const __attribute__((address_space(1))) void*)src,
                                   (__attribute__((address_space(3))) void*)dst, 16, 0, 0);
}

// feature [B,128,N] f32 -> flat [B*N, 128] bf16
__global__ void k_transpose(const float* __restrict__ f, unsigned short* __restrict__ flat){
  __shared__ float tile[32][33];
  int b = blockIdx.z, c0 = blockIdx.y*32, n0 = blockIdx.x*32;
  int tx = threadIdx.x, ty = threadIdx.y;   // (32,8)
  const float* src = f + ((size_t)b*FEATS + c0)*NPTS + n0;
  #pragma unroll
  for(int i=0;i<4;i++) tile[ty+8*i][tx] = src[(size_t)(ty+8*i)*NPTS + tx];
  __syncthreads();
  unsigned short* dst = flat + ((size_t)b*NPTS + n0)*FEATS + c0;
  #pragma unroll
  for(int i=0;i<4;i++) dst[(size_t)(ty+8*i)*FEATS + tx] = f2bf(tile[tx][ty+8*i]);
}

// conv_w f32 [64][128] -> bf16 fragment table: e = (((ks*4+n2)*4+lg)*16+l15)*8+j
__global__ void k_wpack(const float* __restrict__ convw, unsigned short* __restrict__ wp){
  int e = blockIdx.x*256 + threadIdx.x;    // 8192 total
  int j = e & 7, l15 = (e>>3)&15, lg = (e>>7)&3, n2 = (e>>9)&3, ks = e>>11;
  int o = n2*16 + l15, c = ks*32 + lg*8 + j;
  wp[e] = f2bf(convw[o*FEATS + c]);
}

// Laws learned: (256,3) relaxed cap ((256,4) -> 64 VGPR -> spill, r7).
// Perm register-prefetch across MFMAs spills (r8) -> perm via LDS DMA.
// pbuf DOUBLE + counted vmcnt(2), never drain 0 in loop (r10 vs r11: +20%).
// Batched ybuf stores, idx in LDS (r12's scattered stores / shfl-idx lost 20%).
// NEW r13: tbuf[2] + GEMM2 deferred one iteration -> GEMM2(pi-1) executes
// under tr-read(pi) latency, splitting the serial per-point chain.
__global__ __launch_bounds__(256, 3) void k_main(
    const unsigned short* __restrict__ flat,
    const float* __restrict__ perm_g,
    const unsigned short* __restrict__ wpack,
    const int*   __restrict__ idx_g,
    float* __restrict__ out,
    float* __restrict__ stats)
{
  const int t = threadIdx.x, lane = t & 63, w = t >> 6;
  const int l15 = lane & 15, lg = lane >> 4;

  //  gbuf: gather dest [cgrp 0..7][kgrp 0..4][4][16] u16 (DMA, depth-1)
  //  tbuf: GEMM1 output DOUBLE buffer, .view layout XOR-swizzled
  //  pbuf: perm f32 DOUBLE buffer, DMA'd two iterations ahead
  __shared__ __align__(16) unsigned short gbuf_all[WAVES][2560];     // 20480 B
  __shared__ __align__(16) unsigned short tbuf_all[WAVES][2][2560];  // 40960 B
  __shared__ __align__(16) float pbuf_all[WAVES][2][400];            // 12800 B
  __shared__ int   idx_all[WAVES][160];                              // 2560 B (red aliases after)
  __shared__ float ybuf_all[WAVES][4*OUTC];                          // 4096 B
  // total 80,896 B -> 2 blocks/CU

  unsigned short* gbuf = gbuf_all[w];
  unsigned short* tbuf = &tbuf_all[w][0][0];
  int*   idxb = idx_all[w];
  float* ybuf = ybuf_all[w];
  const unsigned gbufb = (unsigned)(size_t)(const __attribute__((address_space(3))) void*)gbuf;

  const int p0 = blockIdx.x*(WAVES*PTS_PER_WAVE) + w*PTS_PER_WAVE;

  // ---- idx prefetch: 160 ints for this wave's 8 points (coalesced) ----
  {
    const int* ib = idx_g + (size_t)p0*KK;
    idxb[lane]      = ib[lane];
    idxb[64+lane]   = ib[64+lane];
    if(lane < 32) idxb[128+lane] = ib[128+lane];
  }

  // ---- per-lane staging map: chunk q = it*64+lane -> (cgrp,kgrp,krem,chalf) ----
  int krowb4[5], colb[5];
  #pragma unroll
  for(int it=0; it<5; it++){
    int q = it*64 + lane;
    int cg = q/40, r = q - cg*40;
    int kgr = r>>3, rem = r&7, krem = rem>>1, chalf = rem&1;
    krowb4[it] = (kgr*4 + krem)*4;      // idx byte offset for row k
    colb[it]   = cg*32 + chalf*16;      // byte offset within flat row
  }

  // ---- tr-read addresses: cross-lane group-transpose semantics ----
  int kg0 = 2*lg;   if(kg0 > 4) kg0 = 0;
  int kg1 = 2*lg+1; if(kg1 > 4) kg1 = 0;
  const unsigned tra0 = gbufb + kg0*128 + l15*8;
  const unsigned tra1 = gbufb + kg1*128 + l15*8;

  // ---- perm offsets into pbuf (clamped in-bounds; A zeroed for k>=20) ----
  const int s2 = (l15 < 4) ? (16 + l15) : 19;
  int koff[8];
  #pragma unroll
  for(int j=0;j<8;j++){ int kb = lg*160 + j*20; koff[j] = (kb > 380) ? 380 : kb; }

  float bsum[4] = {0,0,0,0}, bsq[4] = {0,0,0,0};
  const int kp1 = (l15 < 4) ? (16 + l15) : 19;   // clamped; dup rows masked in epilogue

  #define STAGE_G(PI) do{                                                       \
    int pib_ = (PI)*80;                                                         \
    _Pragma("unroll")                                                           \
    for(int it_=0; it_<5; it_++){                                               \
      int id_ = *(const int*)((const char*)idxb + pib_ + krowb4[it_]);          \
      const char* s_ = (const char*)flat + ((size_t)(unsigned)id_*256) + colb[it_]; \
      gload_lds16(s_, (char*)gbuf + it_*1024);                                  \
    } }while(0)

  #define STAGE_P(PI) do{                                                       \
    const char* ps_ = (const char*)(perm_g + (size_t)(p0+(PI))*400);            \
    char* pd_ = (char*)&pbuf_all[w][(PI)&1][0];                                 \
    gload_lds16(ps_ + (size_t)lane*16, pd_);                                    \
    gload_lds16(ps_ + 576 + (size_t)lane*16, pd_ + 576);                        \
  }while(0)

  // GEMM2 + epilogue for point PJ (reads tbuf half PJ&1, writes ybuf slot PJ&3)
  #define GEMM2_EPI(PJ) do{                                                     \
    f32x4 acc[2][4];                                                            \
    _Pragma("unroll") for(int m2=0;m2<2;m2++)                                   \
      _Pragma("unroll") for(int n2=0;n2<4;n2++){                                \
        f32x4 z={0.f,0.f,0.f,0.f}; acc[m2][n2]=z; }                             \
    const char* tb_ = (const char*)tbuf + ((PJ)&1)*5120;                        \
    _Pragma("unroll")                                                           \
    for(int ks=0; ks<4; ks++){                                                  \
      int a0b = (l15*256 + ks*64 + lg*16) ^ ((l15&7)<<4);                       \
      int a1b = (kp1*256 + ks*64 + lg*16) ^ ((kp1&7)<<4);                       \
      short8 t0 = *(const short8*)(tb_ + a0b);                                  \
      short8 t1 = *(const short8*)(tb_ + a1b);                                  \
      _Pragma("unroll")                                                         \
      for(int n2=0; n2<4; n2++){                                                \
        short8 wf = *(const short8*)(wpack + (ks*4+n2)*512 + lane*8);           \
        acc[0][n2] = __builtin_amdgcn_mfma_f32_16x16x32_bf16(t0, wf, acc[0][n2], 0,0,0); \
        acc[1][n2] = __builtin_amdgcn_mfma_f32_16x16x32_bf16(t1, wf, acc[1][n2], 0,0,0); \
      }                                                                         \
    }                                                                           \
    _Pragma("unroll")                                                           \
    for(int n2=0; n2<4; n2++){                                                  \
      float m0 = fmaxf(fmaxf(acc[0][n2][0], acc[0][n2][1]),                     \
                       fmaxf(acc[0][n2][2], acc[0][n2][3]));                    \
      float m1 = fmaxf(fmaxf(acc[1][n2][0], acc[1][n2][1]),                     \
                       fmaxf(acc[1][n2][2], acc[1][n2][3]));                    \
      float mm = fmaxf(m0, (lg == 0) ? m1 : -3.4e38f);                          \
      mm = fmaxf(mm, __shfl_xor(mm, 16));                                       \
      mm = fmaxf(mm, __shfl_xor(mm, 32));                                       \
      if(lg == 0) ybuf[((PJ)&3)*64 + n2*16 + l15] = mm;                         \
      bsum[n2] += mm; bsq[n2] += mm*mm;                                         \
    }                                                                           \
  }while(0)

  // prologue in-flight: [G(0) x5, P(0) x2, P(1) x2]
  STAGE_G(0); STAGE_P(0); STAGE_P(1);

  const int bb = p0 >> 12, nn0 = p0 & (NPTS-1);

  for(int pi=0; pi<PTS_PER_WAVE; pi++){
    // ---- counted wait: drain G(pi)+P(pi) (oldest), keep P(pi+1) in flight ----
    if(pi == PTS_PER_WAVE-1) asm volatile("s_waitcnt vmcnt(0)" ::: "memory");
    else                     asm volatile("s_waitcnt vmcnt(2)" ::: "memory");

    // ---- flush points 0-3 (epilogues complete as of pi=4's body) ----
    if(pi == 5){
      float* op = out + ((size_t)bb*OUTC + lane)*NPTS + nn0;
      float4 v;
      v.x = ybuf[0*64+lane]; v.y = ybuf[1*64+lane];
      v.z = ybuf[2*64+lane]; v.w = ybuf[3*64+lane];
      *(float4*)op = v;
    }

    // ---- issue tr-reads(pi) + pbuf reads(pi) ----
    short4v lo[8], hi[8];
    #pragma unroll
    for(int nt=0; nt<8; nt++){
      asm volatile("ds_read_b64_tr_b16 %0, %1 offset:%2" : "=v"(lo[nt]) : "v"(tra0), "i"(nt*640));
      asm volatile("ds_read_b64_tr_b16 %0, %1 offset:%2" : "=v"(hi[nt]) : "v"(tra1), "i"(nt*640));
    }
    const float* pb = &pbuf_all[w][pi&1][0];
    float p0r[8], p1r[8];
    #pragma unroll
    for(int j=0;j<8;j++){ p0r[j] = pb[koff[j]+l15]; p1r[j] = pb[koff[j]+s2]; }

    // ---- GEMM2(pi-1)+epilogue(pi-1): independent of tr-reads -> overlaps their latency ----
    if(pi > 0) GEMM2_EPI(pi-1);

    asm volatile("s_waitcnt lgkmcnt(0)" ::: "memory");
    __builtin_amdgcn_sched_barrier(0);                 // rule #18: pin consumers after the wait

    // ---- deep prefetch (gbuf/pbuf[pi&1] now consumed) ----
    if(pi+1 < PTS_PER_WAVE) STAGE_G(pi+1);
    if(pi+2 < PTS_PER_WAVE) STAGE_P(pi+2);

    // ---- pack perm A-frags ----
    short8 a0f, a1f;
    #pragma unroll
    for(int j=0;j<8;j++){
      int kk2 = lg*8 + j;
      a0f[j] = (kk2 < KK) ? (short)f2bf(p0r[j]) : (short)0;
      a1f[j] = (kk2 < KK) ? (short)f2bf(p1r[j]) : (short)0;
    }

    // ---- GEMM1(pi): D[s][c] = sum_k perm[k][s]*gath[k][c] -> tbuf[pi&1] ----
    char* tw = (char*)tbuf + (pi&1)*5120;
    #pragma unroll
    for(int nt=0; nt<8; nt++){
      short8 gf = __builtin_shufflevector(lo[nt], hi[nt], 0,1,2,3,4,5,6,7);
      f32x4 z = {0.f,0.f,0.f,0.f};
      f32x4 c0 = __builtin_amdgcn_mfma_f32_16x16x32_bf16(a0f, gf, z, 0,0,0);
      f32x4 c1 = __builtin_amdgcn_mfma_f32_16x16x32_bf16(a1f, gf, z, 0,0,0);
      const int c = nt*16 + l15;
      {
        int f0 = c*20 + lg*4;                          // s = 4*lg + r
        int byt = (f0*2) ^ (((f0>>7)&7)<<4);
        uint2v pk;
        pk.x = (unsigned)f2bf(c0[0]) | ((unsigned)f2bf(c0[1])<<16);
        pk.y = (unsigned)f2bf(c0[2]) | ((unsigned)f2bf(c0[3])<<16);
        *(uint2v*)(tw + byt) = pk;
      }
      if(lg == 0){
        int f0 = c*20 + 16;                            // s = 16 + r
        int byt = (f0*2) ^ (((f0>>7)&7)<<4);
        uint2v pk;
        pk.x = (unsigned)f2bf(c1[0]) | ((unsigned)f2bf(c1[1])<<16);
        pk.y = (unsigned)f2bf(c1[2]) | ((unsigned)f2bf(c1[3])<<16);
        *(uint2v*)(tw + byt) = pk;
      }
    }
  }

  // ---- drain pipeline: GEMM2+epilogue for last point, flush points 4-7 ----
  GEMM2_EPI(7);
  {
    float* op = out + ((size_t)bb*OUTC + lane)*NPTS + nn0 + 4;
    float4 v;
    v.x = ybuf[0*64+lane]; v.y = ybuf[1*64+lane];
    v.z = ybuf[2*64+lane]; v.w = ybuf[3*64+lane];
    *(float4*)op = v;
  }

  // ---- block-level stats reduction (red aliases idx storage) ----
  float* red = (float*)&idx_all[0][0];
  __syncthreads();
  if(lg == 0){
    #pragma unroll
    for(int n2=0; n2<4; n2++){
      int o = n2*16 + l15;
      red[w*128 + o]      = bsum[n2];
      red[w*128 + 64 + o] = bsq[n2];
    }
  }
  __syncthreads();
  if(w == 0){
    float s = red[lane] + red[128+lane] + red[256+lane] + red[384+lane];
    atomicAdd(&stats[lane], s);
  } else if(w == 1){
    float s = red[64+lane] + red[192+lane] + red[320+lane] + red[448+lane];
    atomicAdd(&stats[64+lane], s);
  }
}

// fused finalize + apply
__global__ void k_bn2(float* __restrict__ out, const float* __restrict__ stats,
                      const float* __restrict__ gamma, const float* __restrict__ beta){
  __shared__ float ss[128];
  int t = threadIdx.x;
  if(t < 64){
    float inv = 1.f/(float)PTOT;
    float mean = stats[t]*inv;
    float var  = stats[64+t]*inv - mean*mean;
    float rstd = rsqrtf(var + 1e-5f);
    float sc = gamma[t]*rstd;
    ss[t]    = sc;
    ss[64+t] = beta[t] - mean*sc;
  }
  __syncthreads();
  int i = blockIdx.x*256 + t;               // over float4s
  float4 v = ((float4*)out)[i];
  int o = (i >> 10) & 63;
  float sc = ss[o], sh = ss[64+o];
  v.x = v.x*sc + sh; v.y = v.y*sc + sh; v.z = v.z*sc + sh; v.w = v.w*sc + sh;
  ((float4*)out)[i] = v;
}

extern "C" void kernel_launch(void* const* d_in, const int* in_sizes, int n_in,
                              void* d_out, int out_size, void* d_ws, size_t ws_size,
                              hipStream_t stream){
  (void)in_sizes; (void)n_in; (void)ws_size;
  const float* feature    = (const float*)d_in[0];
  const float* permatrix  = (const float*)d_in[1];
  const float* conv_w     = (const float*)d_in[2];
  // d_in[3] = conv_b: cancelled exactly by training-mode BatchNorm
  const float* bn_gamma   = (const float*)d_in[4];
  const float* bn_beta    = (const float*)d_in[5];
  const int*   sp_idx     = (const int*)d_in[6];
  float* out = (float*)d_out;

  unsigned short* flat  = (unsigned short*)d_ws;                         // 8 MB
  float* stats          = (float*)((char*)d_ws + (size_t)8*1024*1024);   // 128 f32
  unsigned short* wpack = (unsigned short*)((char*)d_ws + (size_t)8*1024*1024 + 4096); // 16 KB

  hipMemsetAsync(stats, 0, 128*sizeof(float), stream);

  dim3 gT(NPTS/32, FEATS/32, BATCH), bT(32,8);
  k_transpose<<<gT, bT, 0, stream>>>(feature, flat);
  k_wpack<<<dim3(32), dim3(256), 0, stream>>>(conv_w, wpack);

  k_main<<<dim3(PTOT/(WAVES*PTS_PER_WAVE)), dim3(256), 0, stream>>>(
      flat, permatrix, wpack, sp_idx, out, stats);

  k_bn2<<<dim3(out_size/4/256), dim3(256), 0, stream>>>(out, stats, bn_gamma, bn_beta);
}

// Round 14
// 81.505 us; speedup vs baseline: 1.4636x; 1.4636x over previous
//
#include <hip/hip_runtime.h>
#include <hip/hip_bf16.h>

typedef short short8 __attribute__((ext_vector_type(8)));
typedef short short4v __attribute__((ext_vector_type(4)));
typedef float f32x4 __attribute__((ext_vector_type(4)));
typedef unsigned int uint2v __attribute__((ext_vector_type(2)));

#define NPTS 4096
#define BATCH 8
#define PTOT 32768
#define FEATS 128
#define KK 20
#define OUTC 64
#define PTS_PER_WAVE 8
#define WAVES 4

__device__ __forceinline__ unsigned short f2bf(float f){
  union { __hip_bfloat16 h; unsigned short u; } v;
  v.h = __hip_bfloat16(f);
  return v.u;
}

__device__ __forceinline__ void gload_lds16(const void* src, void* dst){
  __builtin_amdgcn_global_load_lds((const __attribute__((address_space(1))) void*)src,
                                   (__attribute__((address_space(3))) void*)dst, 16, 0, 0);
}

// feature [B,128,N] f32 -> flat [B*N, 128] bf16
__global__ void k_transpose(const float* __restrict__ f, unsigned short* __restrict__ flat){
  __shared__ float tile[32][33];
  int b = blockIdx.z, c0 = blockIdx.y*32, n0 = blockIdx.x*32;
  int tx = threadIdx.x, ty = threadIdx.y;   // (32,8)
  const float* src = f + ((size_t)b*FEATS + c0)*NPTS + n0;
  #pragma unroll
  for(int i=0;i<4;i++) tile[ty+8*i][tx] = src[(size_t)(ty+8*i)*NPTS + tx];
  __syncthreads();
  unsigned short* dst = flat + ((size_t)b*NPTS + n0)*FEATS + c0;
  #pragma unroll
  for(int i=0;i<4;i++) dst[(size_t)(ty+8*i)*FEATS + tx] = f2bf(tile[tx][ty+8*i]);
}

// conv_w f32 [64][128] -> bf16 fragment table: e = (((ks*4+n2)*4+lg)*16+l15)*8+j
__global__ void k_wpack(const float* __restrict__ convw, unsigned short* __restrict__ wp){
  int e = blockIdx.x*256 + threadIdx.x;    // 8192 total
  int j = e & 7, l15 = (e>>3)&15, lg = (e>>7)&3, n2 = (e>>9)&3, ks = e>>11;
  int o = n2*16 + l15, c = ks*32 + lg*8 + j;
  wp[e] = f2bf(convw[o*FEATS + c]);
}

// Laws learned: (256,3) relaxed cap ((256,4)->64 VGPR->spill, r7). Perm
// register-prefetch across MFMAs spills (r8). pbuf DOUBLE + counted vmcnt
// (r10 vs r11: +20%). Batched ybuf stores + idx in LDS (r12: -20% without).
// Deferred GEMM2 pipeline -> VGPR 152 -> occupancy collapse (r13).
// NEW r14: W fragments global->LDS. r10's 16 wpack global loads inside GEMM2
// sat YOUNGER than the G/P prefetches in the vmcnt queue; in-order retirement
// meant consuming wf forced a full drain every iteration, silently defeating
// the counted-vmcnt pipeline. With W in LDS, GEMM2 issues zero VMEM and the
// vmcnt(2) schedule holds at true depth.
__global__ __launch_bounds__(256, 3) void k_main(
    const unsigned short* __restrict__ flat,
    const float* __restrict__ perm_g,
    const unsigned short* __restrict__ wpack,
    const int*   __restrict__ idx_g,
    float* __restrict__ out,
    float* __restrict__ stats)
{
  const int t = threadIdx.x, lane = t & 63, w = t >> 6;
  const int l15 = lane & 15, lg = lane >> 4;

  //  gbuf: gather dest [cgrp 0..7][kgrp 0..4][4][16] u16 (DMA, depth-1)
  //  tbuf: GEMM1 output, .view layout XOR-swizzled
  //  pbuf: perm f32 DOUBLE buffer, DMA'd two iterations ahead
  //  W_lds: conv_w fragment table (block-shared, read-only after barrier)
  __shared__ __align__(16) unsigned short gbuf_all[WAVES][2560];     // 20480 B
  __shared__ __align__(16) unsigned short tbuf_all[WAVES][2560];     // 20480 B
  __shared__ __align__(16) float pbuf_all[WAVES][2][400];            // 12800 B
  __shared__ __align__(16) unsigned short W_lds[8192];               // 16384 B
  __shared__ int   idx_all[WAVES][160];                              // 2560 B (red aliases after)
  __shared__ float ybuf_all[WAVES][4*OUTC];                          // 4096 B
  // total 76800 B -> 2 blocks/CU

  unsigned short* gbuf = gbuf_all[w];
  unsigned short* tbuf = tbuf_all[w];
  int*   idxb = idx_all[w];
  float* ybuf = ybuf_all[w];
  const unsigned gbufb = (unsigned)(size_t)(const __attribute__((address_space(3))) void*)gbuf;

  const int p0 = blockIdx.x*(WAVES*PTS_PER_WAVE) + w*PTS_PER_WAVE;

  // ---- idx prefetch: 160 ints for this wave's 8 points (coalesced) ----
  {
    const int* ib = idx_g + (size_t)p0*KK;
    idxb[lane]      = ib[lane];
    idxb[64+lane]   = ib[64+lane];
    if(lane < 32) idxb[128+lane] = ib[128+lane];
  }

  // ---- W table: 16 KB global -> LDS via DMA (lane-linear, layout preserved) ----
  #pragma unroll
  for(int it=0; it<4; it++){
    gload_lds16((const char*)wpack + it*4096 + (size_t)t*16,
                (char*)W_lds + it*4096 + w*1024);
  }
  asm volatile("s_waitcnt vmcnt(0)" ::: "memory");   // drains only W DMAs (none older)
  __syncthreads();                                    // one-time barrier; W_lds ready

  // ---- per-lane staging map: chunk q = it*64+lane -> (cgrp,kgrp,krem,chalf) ----
  int krowb4[5], colb[5];
  #pragma unroll
  for(int it=0; it<5; it++){
    int q = it*64 + lane;
    int cg = q/40, r = q - cg*40;
    int kgr = r>>3, rem = r&7, krem = rem>>1, chalf = rem&1;
    krowb4[it] = (kgr*4 + krem)*4;      // idx byte offset for row k
    colb[it]   = cg*32 + chalf*16;      // byte offset within flat row
  }

  // ---- tr-read addresses: cross-lane group-transpose semantics ----
  int kg0 = 2*lg;   if(kg0 > 4) kg0 = 0;
  int kg1 = 2*lg+1; if(kg1 > 4) kg1 = 0;
  const unsigned tra0 = gbufb + kg0*128 + l15*8;
  const unsigned tra1 = gbufb + kg1*128 + l15*8;

  // ---- perm offsets into pbuf (clamped in-bounds; A zeroed for k>=20) ----
  const int s2 = (l15 < 4) ? (16 + l15) : 19;
  int koff[8];
  #pragma unroll
  for(int j=0;j<8;j++){ int kb = lg*160 + j*20; koff[j] = (kb > 380) ? 380 : kb; }

  float bsum[4] = {0,0,0,0}, bsq[4] = {0,0,0,0};

  #define STAGE_G(PI) do{                                                       \
    int pib_ = (PI)*80;                                                         \
    _Pragma("unroll")                                                           \
    for(int it_=0; it_<5; it_++){                                               \
      int id_ = *(const int*)((const char*)idxb + pib_ + krowb4[it_]);          \
      const char* s_ = (const char*)flat + ((size_t)(unsigned)id_*256) + colb[it_]; \
      gload_lds16(s_, (char*)gbuf + it_*1024);                                  \
    } }while(0)

  #define STAGE_P(PI) do{                                                       \
    const char* ps_ = (const char*)(perm_g + (size_t)(p0+(PI))*400);            \
    char* pd_ = (char*)&pbuf_all[w][(PI)&1][0];                                 \
    gload_lds16(ps_ + (size_t)lane*16, pd_);                                    \
    gload_lds16(ps_ + 576 + (size_t)lane*16, pd_ + 576);                        \
  }while(0)

  // prologue in-flight: [G(0) x5, P(0) x2, P(1) x2]
  STAGE_G(0); STAGE_P(0); STAGE_P(1);

  const int bb = p0 >> 12, nn0 = p0 & (NPTS-1);

  for(int pi=0; pi<PTS_PER_WAVE; pi++){
    // ---- counted wait: drain G(pi)+P(pi) (oldest), keep P(pi+1) in flight ----
    if(pi == PTS_PER_WAVE-1) asm volatile("s_waitcnt vmcnt(0)" ::: "memory");
    else                     asm volatile("s_waitcnt vmcnt(2)" ::: "memory");

    // ---- flush first half of ybuf (points 0-3 complete as of pi=3) ----
    if(pi == 4){
      float* op = out + ((size_t)bb*OUTC + lane)*NPTS + nn0;
      float4 v;
      v.x = ybuf[0*64+lane]; v.y = ybuf[1*64+lane];
      v.z = ybuf[2*64+lane]; v.w = ybuf[3*64+lane];
      *(float4*)op = v;
    }

    // ---- 16 transpose-reads from gbuf + 16 pack reads from pbuf[pi&1] ----
    short4v lo[8], hi[8];
    #pragma unroll
    for(int nt=0; nt<8; nt++){
      asm volatile("ds_read_b64_tr_b16 %0, %1 offset:%2" : "=v"(lo[nt]) : "v"(tra0), "i"(nt*640));
      asm volatile("ds_read_b64_tr_b16 %0, %1 offset:%2" : "=v"(hi[nt]) : "v"(tra1), "i"(nt*640));
    }
    const float* pb = &pbuf_all[w][pi&1][0];
    float p0r[8], p1r[8];
    #pragma unroll
    for(int j=0;j<8;j++){ p0r[j] = pb[koff[j]+l15]; p1r[j] = pb[koff[j]+s2]; }

    asm volatile("s_waitcnt lgkmcnt(0)" ::: "memory");
    __builtin_amdgcn_sched_barrier(0);                 // rule #18: pin consumers after the wait

    // ---- deep prefetch: gather(pi+1) (gbuf consumed), perm(pi+2) (pbuf[pi&1] consumed) ----
    if(pi+1 < PTS_PER_WAVE) STAGE_G(pi+1);
    if(pi+2 < PTS_PER_WAVE) STAGE_P(pi+2);

    // ---- pack perm A-frags (pure VALU on LDS-read values) ----
    short8 a0f, a1f;
    #pragma unroll
    for(int j=0;j<8;j++){
      int kk2 = lg*8 + j;
      a0f[j] = (kk2 < KK) ? (short)f2bf(p0r[j]) : (short)0;
      a1f[j] = (kk2 < KK) ? (short)f2bf(p1r[j]) : (short)0;
    }

    // ---- GEMM1: D[s][c] = sum_k perm[k][s]*gath[k][c]; write .view layout to tbuf ----
    #pragma unroll
    for(int nt=0; nt<8; nt++){
      short8 gf = __builtin_shufflevector(lo[nt], hi[nt], 0,1,2,3,4,5,6,7);
      f32x4 z = {0.f,0.f,0.f,0.f};
      f32x4 c0 = __builtin_amdgcn_mfma_f32_16x16x32_bf16(a0f, gf, z, 0,0,0);
      f32x4 c1 = __builtin_amdgcn_mfma_f32_16x16x32_bf16(a1f, gf, z, 0,0,0);
      const int c = nt*16 + l15;
      {
        int f0 = c*20 + lg*4;                          // s = 4*lg + r
        int byt = (f0*2) ^ (((f0>>7)&7)<<4);
        uint2v pk;
        pk.x = (unsigned)f2bf(c0[0]) | ((unsigned)f2bf(c0[1])<<16);
        pk.y = (unsigned)f2bf(c0[2]) | ((unsigned)f2bf(c0[3])<<16);
        *(uint2v*)((char*)tbuf + byt) = pk;
      }
      if(lg == 0){
        int f0 = c*20 + 16;                            // s = 16 + r
        int byt = (f0*2) ^ (((f0>>7)&7)<<4);
        uint2v pk;
        pk.x = (unsigned)f2bf(c1[0]) | ((unsigned)f2bf(c1[1])<<16);
        pk.y = (unsigned)f2bf(c1[2]) | ((unsigned)f2bf(c1[3])<<16);
        *(uint2v*)((char*)tbuf + byt) = pk;
      }
    }

    // ---- GEMM2: D[kp][o] = sum_c' T[kp][c'] * W[o][c'] — W from LDS, zero VMEM ----
    f32x4 acc[2][4];
    #pragma unroll
    for(int m2=0;m2<2;m2++)
      #pragma unroll
      for(int n2=0;n2<4;n2++){ f32x4 z={0.f,0.f,0.f,0.f}; acc[m2][n2]=z; }

    const int kp1 = (l15 < 4) ? (16 + l15) : 19;       // clamped; dup rows masked in epilogue
    #pragma unroll
    for(int ks=0; ks<4; ks++){
      int a0b = (l15*256 + ks*64 + lg*16) ^ ((l15&7)<<4);
      int a1b = (kp1*256 + ks*64 + lg*16) ^ ((kp1&7)<<4);
      short8 t0 = *(const short8*)((const char*)tbuf + a0b);
      short8 t1 = *(const short8*)((const char*)tbuf + a1b);
      #pragma unroll
      for(int n2=0; n2<4; n2++){
        short8 wf = *(const short8*)((const char*)W_lds + (ks*4+n2)*1024 + lane*16);
        acc[0][n2] = __builtin_amdgcn_mfma_f32_16x16x32_bf16(t0, wf, acc[0][n2], 0,0,0);
        acc[1][n2] = __builtin_amdgcn_mfma_f32_16x16x32_bf16(t1, wf, acc[1][n2], 0,0,0);
      }
    }

    // ---- epilogue: max over kp, buffer y in LDS, BN partials ----
    #pragma unroll
    for(int n2=0; n2<4; n2++){
      float m0 = fmaxf(fmaxf(acc[0][n2][0], acc[0][n2][1]),
                       fmaxf(acc[0][n2][2], acc[0][n2][3]));
      float m1 = fmaxf(fmaxf(acc[1][n2][0], acc[1][n2][1]),
                       fmaxf(acc[1][n2][2], acc[1][n2][3]));
      float mm = fmaxf(m0, (lg == 0) ? m1 : -3.4e38f);
      mm = fmaxf(mm, __shfl_xor(mm, 16));
      mm = fmaxf(mm, __shfl_xor(mm, 32));
      if(lg == 0) ybuf[(pi&3)*64 + n2*16 + l15] = mm;  // conv bias cancels under BN
      bsum[n2] += mm; bsq[n2] += mm*mm;
    }
  }

  // ---- flush second half of ybuf (points 4..7) ----
  {
    float* op = out + ((size_t)bb*OUTC + lane)*NPTS + nn0 + 4;
    float4 v;
    v.x = ybuf[0*64+lane]; v.y = ybuf[1*64+lane];
    v.z = ybuf[2*64+lane]; v.w = ybuf[3*64+lane];
    *(float4*)op = v;
  }

  // ---- block-level stats reduction (red aliases idx storage) ----
  float* red = (float*)&idx_all[0][0];
  __syncthreads();
  if(lg == 0){
    #pragma unroll
    for(int n2=0; n2<4; n2++){
      int o = n2*16 + l15;
      red[w*128 + o]      = bsum[n2];
      red[w*128 + 64 + o] = bsq[n2];
    }
  }
  __syncthreads();
  if(w == 0){
    float s = red[lane] + red[128+lane] + red[256+lane] + red[384+lane];
    atomicAdd(&stats[lane], s);
  } else if(w == 1){
    float s = red[64+lane] + red[192+lane] + red[320+lane] + red[448+lane];
    atomicAdd(&stats[64+lane], s);
  }
}

// fused finalize + apply
__global__ void k_bn2(float* __restrict__ out, const float* __restrict__ stats,
                      const float* __restrict__ gamma, const float* __restrict__ beta){
  __shared__ float ss[128];
  int t = threadIdx.x;
  if(t < 64){
    float inv = 1.f/(float)PTOT;
    float mean = stats[t]*inv;
    float var  = stats[64+t]*inv - mean*mean;
    float rstd = rsqrtf(var + 1e-5f);
    float sc = gamma[t]*rstd;
    ss[t]    = sc;
    ss[64+t] = beta[t] - mean*sc;
  }
  __syncthreads();
  int i = blockIdx.x*256 + t;               // over float4s
  float4 v = ((float4*)out)[i];
  int o = (i >> 10) & 63;
  float sc = ss[o], sh = ss[64+o];
  v.x = v.x*sc + sh; v.y = v.y*sc + sh; v.z = v.z*sc + sh; v.w = v.w*sc + sh;
  ((float4*)out)[i] = v;
}

extern "C" void kernel_launch(void* const* d_in, const int* in_sizes, int n_in,
                              void* d_out, int out_size, void* d_ws, size_t ws_size,
                              hipStream_t stream){
  (void)in_sizes; (void)n_in; (void)ws_size;
  const float* feature    = (const float*)d_in[0];
  const float* permatrix  = (const float*)d_in[1];
  const float* conv_w     = (const float*)d_in[2];
  // d_in[3] = conv_b: cancelled exactly by training-mode BatchNorm
  const float* bn_gamma   = (const float*)d_in[4];
  const float* bn_beta    = (const float*)d_in[5];
  const int*   sp_idx     = (const int*)d_in[6];
  float* out = (float*)d_out;

  unsigned short* flat  = (unsigned short*)d_ws;                         // 8 MB
  float* stats          = (float*)((char*)d_ws + (size_t)8*1024*1024);   // 128 f32
  unsigned short* wpack = (unsigned short*)((char*)d_ws + (size_t)8*1024*1024 + 4096); // 16 KB

  hipMemsetAsync(stats, 0, 128*sizeof(float), stream);

  dim3 gT(NPTS/32, FEATS/32, BATCH), bT(32,8);
  k_transpose<<<gT, bT, 0, stream>>>(feature, flat);
  k_wpack<<<dim3(32), dim3(256), 0, stream>>>(conv_w, wpack);

  k_main<<<dim3(PTOT/(WAVES*PTS_PER_WAVE)), dim3(256), 0, stream>>>(
      flat, permatrix, wpack, sp_idx, out, stats);

  k_bn2<<<dim3(out_size/4/256), dim3(256), 0, stream>>>(out, stats, bn_gamma, bn_beta);
}